// Round 9
// baseline (123.976 us; speedup 1.0000x reference)
//
#include <hip/hip_runtime.h>
#include <hip/hip_bf16.h>
#include <math.h>

#define HS 64
#define NE 128
#define TSEQ 2048

typedef short s8v __attribute__((ext_vector_type(8)));   // 8 bf16 (4 VGPRs) MFMA A/B frag
typedef float f4v __attribute__((ext_vector_type(4)));   // 4 fp32 MFMA C/D frag

__device__ __forceinline__ unsigned short f2bf(float f) {
    unsigned int u = __float_as_uint(f);
    u += 0x7FFFu + ((u >> 16) & 1u);   // RNE (no NaN inputs here)
    return (unsigned short)(u >> 16);
}

__device__ __forceinline__ unsigned int pkbf(float a, float b) {
    union { __hip_bfloat162 h; unsigned int u; } cv;
    cv.h = __float22bfloat162_rn(make_float2(a, b));
    return cv.u;
}

__device__ __forceinline__ s8v mk_s8v(unsigned int a, unsigned int b,
                                      unsigned int c, unsigned int d) {
    union { unsigned int u[4]; s8v v; } cv;
    cv.u[0] = a; cv.u[1] = b; cv.u[2] = c; cv.u[3] = d;
    return cv.v;
}

// raw v_exp_f32 (2^x). exp2f without -ffast-math is an OCML call.
__device__ __forceinline__ float fexp2(float x) {
    float r;
    asm("v_exp_f32 %0, %1" : "=v"(r) : "v"(x));
    return r;
}

// async global->LDS, 16B per lane (dest = wave-uniform base + lane*16).
__device__ __forceinline__ void glds16(const unsigned short* g, unsigned short* l) {
    __builtin_amdgcn_global_load_lds(
        (const __attribute__((address_space(1))) unsigned int*)g,
        (__attribute__((address_space(3))) unsigned int*)l,
        16, 0, 0);
}

// ---------------- W -> bf16, transposed wt[mat][n][k], q pre-scaled ----------------
__global__ __launch_bounds__(256) void wconv(
    const float* __restrict__ Wq, const float* __restrict__ Wk,
    const float* __restrict__ Wv, unsigned short* __restrict__ wt)
{
    const int o0 = (blockIdx.x * 256 + threadIdx.x) * 2;   // 24576 elems total
    const int mat = o0 >> 13;
    const int n = (o0 >> 7) & 63;
    const int k = o0 & 127;        // even
    const float* W = (mat == 0) ? Wq : (mat == 1) ? Wk : Wv;
    const float s = (mat == 0) ? 0.18033688f : 1.0f;   // 64^-0.5 * log2(e)
    unsigned int lo = f2bf(W[k * HS + n] * s);
    unsigned int hi = f2bf(W[(k + 1) * HS + n] * s);
    *(unsigned int*)(wt + o0) = lo | (hi << 16);
}

// ---------------- QKV projection: swapped operands, no LDS, no barriers ----------
// C = W^T · x^T : C-frag rows = outdims (quad*4+r), cols = t (li). q/k epilogue
// = direct 8B stores (4 consecutive dims/lane); v = dim-major 2B scatter in
// 32B-coalesced quad runs. 2048 single-wave blocks, 16 t's each; 48 independent
// W A-frag b128 loads from L2-resident wt + 8 x loads -> 48 MFMA. Zero sync.
__global__ __launch_bounds__(64) void qkv(
    const float* __restrict__ x, const unsigned short* __restrict__ wt,
    const float* __restrict__ bq, const float* __restrict__ bk,
    const float* __restrict__ bv,
    unsigned short* __restrict__ qo, unsigned short* __restrict__ ko,
    unsigned short* __restrict__ vt)
{
    const int tid = threadIdx.x;
    const int quad = tid >> 4;
    const int li = tid & 15;
    const size_t t0 = (size_t)blockIdx.x * 16;
    const size_t t = t0 + li;

    // B-frags: one t per lane (n=li), k = ks*32 + quad*8 + j, fp32 -> bf16
    s8v xb[4];
    const float* xr = x + t * NE + quad * 8;
#pragma unroll
    for (int ks = 0; ks < 4; ++ks) {
        float4 f0 = *(const float4*)(xr + ks * 32);
        float4 f1 = *(const float4*)(xr + ks * 32 + 4);
        xb[ks] = mk_s8v(pkbf(f0.x, f0.y), pkbf(f0.z, f0.w),
                        pkbf(f1.x, f1.y), pkbf(f1.z, f1.w));
    }

    f4v acc[12];
#pragma unroll
    for (int mt = 0; mt < 12; ++mt) acc[mt] = (f4v){0.f, 0.f, 0.f, 0.f};

    // A-frags: W^T rows (m = mt*16+li = outdim), k contiguous — wt as-is
#pragma unroll
    for (int mt = 0; mt < 12; ++mt) {
        const unsigned short* wr = wt + (mt * 16 + li) * NE + quad * 8;
#pragma unroll
        for (int ks = 0; ks < 4; ++ks) {
            s8v af = *(const s8v*)(wr + ks * 32);
            acc[mt] = __builtin_amdgcn_mfma_f32_16x16x32_bf16(af, xb[ks], acc[mt], 0, 0, 0);
        }
    }

    const int d0 = quad * 4;
    const float sq = 0.18033688f;

    // q: dims mt*16+d0..+3 for row t — one 8B store per m-tile
#pragma unroll
    for (int mt = 0; mt < 4; ++mt) {
        float4 bb = *(const float4*)(bq + mt * 16 + d0);
        *(ushort4*)(qo + t * HS + mt * 16 + d0) = (ushort4){
            f2bf(acc[mt][0] + bb.x * sq), f2bf(acc[mt][1] + bb.y * sq),
            f2bf(acc[mt][2] + bb.z * sq), f2bf(acc[mt][3] + bb.w * sq)};
    }
    // k
#pragma unroll
    for (int mt = 0; mt < 4; ++mt) {
        float4 bb = *(const float4*)(bk + mt * 16 + d0);
        *(ushort4*)(ko + t * HS + mt * 16 + d0) = (ushort4){
            f2bf(acc[mt + 4][0] + bb.x), f2bf(acc[mt + 4][1] + bb.y),
            f2bf(acc[mt + 4][2] + bb.z), f2bf(acc[mt + 4][3] + bb.w)};
    }
    // v: dim-major vt[b][dim][t]; per (mt,r) the 16 lanes of a quad write
    // 32B-contiguous t-runs
    const size_t bidx = t0 >> 11;
    const size_t trow = t & 2047;
#pragma unroll
    for (int mt = 0; mt < 4; ++mt) {
        float4 bb = *(const float4*)(bv + mt * 16 + d0);
#pragma unroll
        for (int r = 0; r < 4; ++r) {
            vt[(bidx * HS + mt * 16 + d0 + r) * TSEQ + trow] =
                f2bf(acc[mt + 8][r] + (&bb.x)[r]);
        }
    }
}

// ---------------- Flash attention, balanced chunks + partials (R8, unchanged) ------
__global__ __launch_bounds__(256) void attn_main(
    const unsigned short* __restrict__ qb,
    const unsigned short* __restrict__ kb,
    const unsigned short* __restrict__ vtb,
    float* __restrict__ out, float* __restrict__ pbuf, float* __restrict__ lsbuf)
{
    __shared__ unsigned short Ks[2][64 * 64];
    __shared__ unsigned short Vs[2][64 * 64];
    __shared__ __align__(16) unsigned short Ps[4][1024];   // granule-transposed P

    const int tid = threadIdx.x;
    const int w = tid >> 6;
    const int lane = tid & 63;
    const int quad = lane >> 4;
    const int li = lane & 15;

    const int id = blockIdx.x;
    const int b = id / 80;
    const int u = 79 - (id - b * 80);   // big chunks first
    int qt, c, nc;
    if (u < 8)       { qt = u;                 c = 0;            nc = 1; }
    else if (u < 24) { qt = 8 + ((u - 8) >> 1);  c = (u - 8) & 1;  nc = 2; }
    else if (u < 48) { qt = 16 + (u - 24) / 3;   c = (u - 24) % 3; nc = 3; }
    else             { qt = 24 + ((u - 48) >> 2); c = (u - 48) & 3; nc = 4; }
    const int tb = c * 8;
    const int te_ = tb + 8;
    const int te = (te_ < qt + 1) ? te_ : (qt + 1);

    const size_t base = (size_t)b * TSEQ;
    const int t0 = qt << 6;
    const int qrow = t0 + w * 16 + li;

    const unsigned short* qrp = qb + (base + qrow) * HS + quad * 8;
    s8v qf0 = *(const s8v*)qrp;
    s8v qf1 = *(const s8v*)(qrp + 32);

    const int rA = w * 8 + (lane >> 3);
    const int csw = (lane & 7) ^ (rA & 7);
    const unsigned short* kgA = kb + (base + rA) * HS + csw * 8;
    const unsigned short* kgB = kgA + 32 * HS;
    const unsigned short* vgA = vtb + ((size_t)b * HS + rA) * TSEQ + csw * 8;
    const unsigned short* vgB = vgA + 32 * TSEQ;
    const int ldsA = w * 512 + lane * 8;
    const int ldsB = 2048 + w * 512 + lane * 8;

    glds16(kgA + (size_t)tb * 4096, &Ks[0][ldsA]);
    glds16(kgB + (size_t)tb * 4096, &Ks[0][ldsB]);
    glds16(vgA + (size_t)tb * 64,   &Vs[0][ldsA]);
    glds16(vgB + (size_t)tb * 64,   &Vs[0][ldsB]);

    f4v c_o[4];
#pragma unroll
    for (int f = 0; f < 4; ++f) c_o[f] = (f4v){0.f, 0.f, 0.f, 0.f};
    float lsum = 0.f;

    char* pbse = (char*)&Ps[w][0];
    const int swz0 = (quad ^ (li & 7)) * 8;
    const int swz1 = ((4 + quad) ^ (li & 7)) * 8;

    __syncthreads();

    for (int tl = tb; tl < te; ++tl) {
        const int bi = (tl - tb) & 1;
        if (tl + 1 < te) {
            const int nb = bi ^ 1;
            glds16(kgA + (size_t)(tl + 1) * 4096, &Ks[nb][ldsA]);
            glds16(kgB + (size_t)(tl + 1) * 4096, &Ks[nb][ldsB]);
            glds16(vgA + (size_t)(tl + 1) * 64,   &Vs[nb][ldsA]);
            glds16(vgB + (size_t)(tl + 1) * 64,   &Vs[nb][ldsB]);
        }
        const unsigned short* Kc = &Ks[bi][0];
        const unsigned short* Vc = &Vs[bi][0];
        const bool diag = (tl == qt);

        float pr[4][4];
        float rs = 0.f;
#pragma unroll
        for (int kt = 0; kt < 4; ++kt) {
            const unsigned short* krow = Kc + (kt * 16 + li) * 64;
            s8v k0 = *(const s8v*)(krow + swz0);
            s8v k1 = *(const s8v*)(krow + swz1);
            f4v cst = (f4v){0.f, 0.f, 0.f, 0.f};
            cst = __builtin_amdgcn_mfma_f32_16x16x32_bf16(k0, qf0, cst, 0, 0, 0);
            cst = __builtin_amdgcn_mfma_f32_16x16x32_bf16(k1, qf1, cst, 0, 0, 0);
            if (diag) {
                const int key0 = (tl << 6) + kt * 16 + quad * 4;
#pragma unroll
                for (int rr = 0; rr < 4; ++rr)
                    if (key0 + rr > qrow) cst[rr] = -INFINITY;
            }
#pragma unroll
            for (int rr = 0; rr < 4; ++rr) {
                pr[kt][rr] = fexp2(cst[rr]);
                rs += pr[kt][rr];
            }
        }
        lsum += rs;

#pragma unroll
        for (int kt = 0; kt < 4; ++kt) {
            *(uint2*)(pbse + (kt * 2 + (quad >> 1)) * 256 + li * 16 + (quad & 1) * 8) =
                make_uint2(pkbf(pr[kt][0], pr[kt][1]), pkbf(pr[kt][2], pr[kt][3]));
        }
        s8v pf0 = *(const s8v*)(pbse + lane * 16);
        s8v pf1 = *(const s8v*)(pbse + 1024 + lane * 16);

#pragma unroll
        for (int f = 0; f < 4; ++f) {
            const unsigned short* vrow = Vc + (f * 16 + li) * 64;
            s8v v0 = *(const s8v*)(vrow + swz0);
            s8v v1 = *(const s8v*)(vrow + swz1);
            c_o[f] = __builtin_amdgcn_mfma_f32_16x16x32_bf16(v0, pf0, c_o[f], 0, 0, 0);
            c_o[f] = __builtin_amdgcn_mfma_f32_16x16x32_bf16(v1, pf1, c_o[f], 0, 0, 0);
        }

        __syncthreads();
    }

    lsum += __shfl_xor(lsum, 16);
    lsum += __shfl_xor(lsum, 32);

    if (nc == 1) {
        const float inv = 1.0f / lsum;
        float* orow = out + (base + qrow) * HS + quad * 4;
#pragma unroll
        for (int f = 0; f < 4; ++f) {
            f4v res = c_o[f];
            res[0] *= inv; res[1] *= inv; res[2] *= inv; res[3] *= inv;
            *(f4v*)(orow + f * 16) = res;
        }
    } else {
        const int local = (qt < 16) ? (qt - 8) * 2 + c
                        : (qt < 24) ? 16 + (qt - 16) * 3 + c
                                    : 40 + (qt - 24) * 4 + c;
        const int pidx = b * 72 + local;
        float* pc = pbuf + (size_t)pidx * 4096 + (w * 16 + li) * 64;
#pragma unroll
        for (int f = 0; f < 4; ++f)
            *(f4v*)(pc + f * 16 + quad * 4) = c_o[f];
        if (quad == 0)
            lsbuf[(size_t)pidx * 64 + w * 16 + li] = lsum;
    }
}

// ---------------- Partial combine + normalize (qt >= 8) ----------------
__global__ __launch_bounds__(256) void attn_reduce(
    const float* __restrict__ pbuf, const float* __restrict__ lsbuf,
    float* __restrict__ out)
{
    const int g = blockIdx.x;            // 384 = 16 batches * 24 q-tiles
    const int b = g / 24;
    const int r = g - b * 24;
    int qt, lbase, nc;
    if (r < 8)       { qt = 8 + r;        lbase = 2 * r;            nc = 2; }
    else if (r < 16) { qt = 16 + (r - 8); lbase = 16 + 3 * (r - 8); nc = 3; }
    else             { qt = 24 + (r - 16); lbase = 40 + 4 * (r - 16); nc = 4; }
    const int pidx0 = b * 72 + lbase;

    const int tid = threadIdx.x;
    const int row = tid >> 2;
    const int seg = tid & 3;

    float4 acc[4];
#pragma unroll
    for (int j = 0; j < 4; ++j) acc[j] = make_float4(0.f, 0.f, 0.f, 0.f);
    float ls = 0.f;

    for (int cc = 0; cc < nc; ++cc) {
        const float* pc = pbuf + (size_t)(pidx0 + cc) * 4096 + row * 64 + seg * 16;
#pragma unroll
        for (int j = 0; j < 4; ++j) {
            float4 v = *(const float4*)(pc + j * 4);
            acc[j].x += v.x; acc[j].y += v.y; acc[j].z += v.z; acc[j].w += v.w;
        }
        ls += lsbuf[(size_t)(pidx0 + cc) * 64 + row];
    }
    const float inv = 1.0f / ls;
    float* orow = out + ((size_t)b * TSEQ + (qt << 6) + row) * HS + seg * 16;
#pragma unroll
    for (int j = 0; j < 4; ++j) {
        *(float4*)(orow + j * 4) = make_float4(acc[j].x * inv, acc[j].y * inv,
                                               acc[j].z * inv, acc[j].w * inv);
    }
}

extern "C" void kernel_launch(void* const* d_in, const int* in_sizes, int n_in,
                              void* d_out, int out_size, void* d_ws, size_t ws_size,
                              hipStream_t stream) {
    const float* x  = (const float*)d_in[0];
    const float* Wk = (const float*)d_in[1];
    const float* bk = (const float*)d_in[2];
    const float* Wq = (const float*)d_in[3];
    const float* bq = (const float*)d_in[4];
    const float* Wv = (const float*)d_in[5];
    const float* bv = (const float*)d_in[6];
    float* outp = (float*)d_out;

    const size_t elems = (size_t)16 * TSEQ * HS;  // 2M per tensor
    unsigned short* qbuf = (unsigned short*)d_ws;
    unsigned short* kbuf = qbuf + elems;
    unsigned short* vbuf = kbuf + elems;          // transposed [b][dim][t]
    unsigned short* wtb  = vbuf + elems;          // [3][64][128] bf16
    float* pbuf  = (float*)(wtb + 32768);         // [1152][64][64] fp32 partials
    float* lsbuf = pbuf + (size_t)1152 * 4096;    // [1152][64] lsums

    wconv<<<48, 256, 0, stream>>>(Wq, Wk, Wv, wtb);
    qkv<<<2048, 64, 0, stream>>>(x, wtb, bq, bk, bv, qbuf, kbuf, vbuf);
    attn_main<<<1280, 256, 0, stream>>>(qbuf, kbuf, vbuf, outp, pbuf, lsbuf);
    attn_reduce<<<384, 256, 0, stream>>>(pbuf, lsbuf, outp);
}

// Round 10
// 117.330 us; speedup vs baseline: 1.0566x; 1.0566x over previous
//
#include <hip/hip_runtime.h>
#include <hip/hip_bf16.h>
#include <math.h>

#define HS 64
#define NE 128
#define TSEQ 2048

typedef short s8v __attribute__((ext_vector_type(8)));   // 8 bf16 (4 VGPRs) MFMA A/B frag
typedef float f4v __attribute__((ext_vector_type(4)));   // 4 fp32 MFMA C/D frag

__device__ __forceinline__ unsigned short f2bf(float f) {
    unsigned int u = __float_as_uint(f);
    u += 0x7FFFu + ((u >> 16) & 1u);   // RNE (no NaN inputs here)
    return (unsigned short)(u >> 16);
}

__device__ __forceinline__ unsigned int pkbf(float a, float b) {
    union { __hip_bfloat162 h; unsigned int u; } cv;
    cv.h = __float22bfloat162_rn(make_float2(a, b));
    return cv.u;
}

__device__ __forceinline__ s8v mk_s8v(unsigned int a, unsigned int b,
                                      unsigned int c, unsigned int d) {
    union { unsigned int u[4]; s8v v; } cv;
    cv.u[0] = a; cv.u[1] = b; cv.u[2] = c; cv.u[3] = d;
    return cv.v;
}

// raw v_exp_f32 (2^x). exp2f without -ffast-math is an OCML call.
__device__ __forceinline__ float fexp2(float x) {
    float r;
    asm("v_exp_f32 %0, %1" : "=v"(r) : "v"(x));
    return r;
}

// async global->LDS, 16B per lane (dest = wave-uniform base + lane*16).
__device__ __forceinline__ void glds16(const unsigned short* g, unsigned short* l) {
    __builtin_amdgcn_global_load_lds(
        (const __attribute__((address_space(1))) unsigned int*)g,
        (__attribute__((address_space(3))) unsigned int*)l,
        16, 0, 0);
}

// -------- W -> bf16 in MFMA-tiled granule order, q pre-scaled --------
// granule g (16B) = A-frag of lane (g&63) for tile (mt = g>>8, ks = (g>>6)&3):
//   elems W^T[m = mt*16 + (g&15)][k = ks*32 + ((g>>4)&3)*8 + j], j=0..7
// so qkv's A-frag load for (mt,ks) is wt + (mt*4+ks)*512 + lane*8 — one
// contiguous, fully-coalesced 1KB per instruction.
__global__ __launch_bounds__(256) void wconv(
    const float* __restrict__ Wq, const float* __restrict__ Wk,
    const float* __restrict__ Wv, unsigned short* __restrict__ wt)
{
    const int g = blockIdx.x * 256 + threadIdx.x;   // 0..3071 granules
    const int lane = g & 63;
    const int mtks = g >> 6;
    const int mt = mtks >> 2;
    const int ks = mtks & 3;
    const int li = lane & 15;
    const int quad = lane >> 4;
    const int m = mt * 16 + li;          // global outdim 0..191
    const int mat = m >> 6;
    const int n = m & 63;                // outdim within matrix
    const int k0 = ks * 32 + quad * 8;
    const float* W = (mat == 0) ? Wq : (mat == 1) ? Wk : Wv;
    const float s = (mat == 0) ? 0.18033688f : 1.0f;   // 64^-0.5 * log2(e)

    unsigned int u[4];
#pragma unroll
    for (int h = 0; h < 4; ++h)
        u[h] = pkbf(W[(k0 + 2 * h) * HS + n] * s, W[(k0 + 2 * h + 1) * HS + n] * s);
    *(s8v*)(wt + (size_t)g * 8) = mk_s8v(u[0], u[1], u[2], u[3]);
}

// ---------------- QKV projection: swapped operands, tiled-coalesced W ----------
// C = W^T · x^T : C-frag rows = outdims, cols = t. Direct 8B q/k stores; v =
// dim-major scatter in 32B quad runs. 2048 single-wave blocks; 48 fully-
// coalesced A-frag loads (1KB/instr, L1-resident) + 8 x loads -> 48 MFMA.
__global__ __launch_bounds__(64) void qkv(
    const float* __restrict__ x, const unsigned short* __restrict__ wt,
    const float* __restrict__ bq, const float* __restrict__ bk,
    const float* __restrict__ bv,
    unsigned short* __restrict__ qo, unsigned short* __restrict__ ko,
    unsigned short* __restrict__ vt)
{
    const int tid = threadIdx.x;          // == lane (single wave)
    const int quad = tid >> 4;
    const int li = tid & 15;
    const size_t t0 = (size_t)blockIdx.x * 16;
    const size_t t = t0 + li;

    // B-frags: one t per lane (n=li), k = ks*32 + quad*8 + j, fp32 -> bf16
    s8v xb[4];
    const float* xr = x + t * NE + quad * 8;
#pragma unroll
    for (int ks = 0; ks < 4; ++ks) {
        float4 f0 = *(const float4*)(xr + ks * 32);
        float4 f1 = *(const float4*)(xr + ks * 32 + 4);
        xb[ks] = mk_s8v(pkbf(f0.x, f0.y), pkbf(f0.z, f0.w),
                        pkbf(f1.x, f1.y), pkbf(f1.z, f1.w));
    }

    f4v acc[12];
#pragma unroll
    for (int mt = 0; mt < 12; ++mt) acc[mt] = (f4v){0.f, 0.f, 0.f, 0.f};

    // A-frags: tiled layout — lane-linear contiguous loads
#pragma unroll
    for (int mt = 0; mt < 12; ++mt) {
#pragma unroll
        for (int ks = 0; ks < 4; ++ks) {
            s8v af = *(const s8v*)(wt + ((mt * 4 + ks) << 9) + tid * 8);
            acc[mt] = __builtin_amdgcn_mfma_f32_16x16x32_bf16(af, xb[ks], acc[mt], 0, 0, 0);
        }
    }

    const int d0 = quad * 4;
    const float sq = 0.18033688f;

    // q: dims mt*16+d0..+3 for row t — one 8B store per m-tile
#pragma unroll
    for (int mt = 0; mt < 4; ++mt) {
        float4 bb = *(const float4*)(bq + mt * 16 + d0);
        *(ushort4*)(qo + t * HS + mt * 16 + d0) = (ushort4){
            f2bf(acc[mt][0] + bb.x * sq), f2bf(acc[mt][1] + bb.y * sq),
            f2bf(acc[mt][2] + bb.z * sq), f2bf(acc[mt][3] + bb.w * sq)};
    }
    // k
#pragma unroll
    for (int mt = 0; mt < 4; ++mt) {
        float4 bb = *(const float4*)(bk + mt * 16 + d0);
        *(ushort4*)(ko + t * HS + mt * 16 + d0) = (ushort4){
            f2bf(acc[mt + 4][0] + bb.x), f2bf(acc[mt + 4][1] + bb.y),
            f2bf(acc[mt + 4][2] + bb.z), f2bf(acc[mt + 4][3] + bb.w)};
    }
    // v: dim-major vt[b][dim][t]; per (mt,r) a quad's 16 lanes write 32B runs
    const size_t bidx = t0 >> 11;
    const size_t trow = t & 2047;
#pragma unroll
    for (int mt = 0; mt < 4; ++mt) {
        float4 bb = *(const float4*)(bv + mt * 16 + d0);
#pragma unroll
        for (int r = 0; r < 4; ++r) {
            vt[(bidx * HS + mt * 16 + d0 + r) * TSEQ + trow] =
                f2bf(acc[mt + 8][r] + (&bb.x)[r]);
        }
    }
}

// ---------------- Flash attention, balanced chunks + partials (R8, unchanged) ------
__global__ __launch_bounds__(256) void attn_main(
    const unsigned short* __restrict__ qb,
    const unsigned short* __restrict__ kb,
    const unsigned short* __restrict__ vtb,
    float* __restrict__ out, float* __restrict__ pbuf, float* __restrict__ lsbuf)
{
    __shared__ unsigned short Ks[2][64 * 64];
    __shared__ unsigned short Vs[2][64 * 64];
    __shared__ __align__(16) unsigned short Ps[4][1024];   // granule-transposed P

    const int tid = threadIdx.x;
    const int w = tid >> 6;
    const int lane = tid & 63;
    const int quad = lane >> 4;
    const int li = lane & 15;

    const int id = blockIdx.x;
    const int b = id / 80;
    const int u = 79 - (id - b * 80);   // big chunks first
    int qt, c, nc;
    if (u < 8)       { qt = u;                 c = 0;            nc = 1; }
    else if (u < 24) { qt = 8 + ((u - 8) >> 1);  c = (u - 8) & 1;  nc = 2; }
    else if (u < 48) { qt = 16 + (u - 24) / 3;   c = (u - 24) % 3; nc = 3; }
    else             { qt = 24 + ((u - 48) >> 2); c = (u - 48) & 3; nc = 4; }
    const int tb = c * 8;
    const int te_ = tb + 8;
    const int te = (te_ < qt + 1) ? te_ : (qt + 1);

    const size_t base = (size_t)b * TSEQ;
    const int t0 = qt << 6;
    const int qrow = t0 + w * 16 + li;

    const unsigned short* qrp = qb + (base + qrow) * HS + quad * 8;
    s8v qf0 = *(const s8v*)qrp;
    s8v qf1 = *(const s8v*)(qrp + 32);

    const int rA = w * 8 + (lane >> 3);
    const int csw = (lane & 7) ^ (rA & 7);
    const unsigned short* kgA = kb + (base + rA) * HS + csw * 8;
    const unsigned short* kgB = kgA + 32 * HS;
    const unsigned short* vgA = vtb + ((size_t)b * HS + rA) * TSEQ + csw * 8;
    const unsigned short* vgB = vgA + 32 * TSEQ;
    const int ldsA = w * 512 + lane * 8;
    const int ldsB = 2048 + w * 512 + lane * 8;

    glds16(kgA + (size_t)tb * 4096, &Ks[0][ldsA]);
    glds16(kgB + (size_t)tb * 4096, &Ks[0][ldsB]);
    glds16(vgA + (size_t)tb * 64,   &Vs[0][ldsA]);
    glds16(vgB + (size_t)tb * 64,   &Vs[0][ldsB]);

    f4v c_o[4];
#pragma unroll
    for (int f = 0; f < 4; ++f) c_o[f] = (f4v){0.f, 0.f, 0.f, 0.f};
    float lsum = 0.f;

    char* pbse = (char*)&Ps[w][0];
    const int swz0 = (quad ^ (li & 7)) * 8;
    const int swz1 = ((4 + quad) ^ (li & 7)) * 8;

    __syncthreads();

    for (int tl = tb; tl < te; ++tl) {
        const int bi = (tl - tb) & 1;
        if (tl + 1 < te) {
            const int nb = bi ^ 1;
            glds16(kgA + (size_t)(tl + 1) * 4096, &Ks[nb][ldsA]);
            glds16(kgB + (size_t)(tl + 1) * 4096, &Ks[nb][ldsB]);
            glds16(vgA + (size_t)(tl + 1) * 64,   &Vs[nb][ldsA]);
            glds16(vgB + (size_t)(tl + 1) * 64,   &Vs[nb][ldsB]);
        }
        const unsigned short* Kc = &Ks[bi][0];
        const unsigned short* Vc = &Vs[bi][0];
        const bool diag = (tl == qt);

        float pr[4][4];
        float rs = 0.f;
#pragma unroll
        for (int kt = 0; kt < 4; ++kt) {
            const unsigned short* krow = Kc + (kt * 16 + li) * 64;
            s8v k0 = *(const s8v*)(krow + swz0);
            s8v k1 = *(const s8v*)(krow + swz1);
            f4v cst = (f4v){0.f, 0.f, 0.f, 0.f};
            cst = __builtin_amdgcn_mfma_f32_16x16x32_bf16(k0, qf0, cst, 0, 0, 0);
            cst = __builtin_amdgcn_mfma_f32_16x16x32_bf16(k1, qf1, cst, 0, 0, 0);
            if (diag) {
                const int key0 = (tl << 6) + kt * 16 + quad * 4;
#pragma unroll
                for (int rr = 0; rr < 4; ++rr)
                    if (key0 + rr > qrow) cst[rr] = -INFINITY;
            }
#pragma unroll
            for (int rr = 0; rr < 4; ++rr) {
                pr[kt][rr] = fexp2(cst[rr]);
                rs += pr[kt][rr];
            }
        }
        lsum += rs;

#pragma unroll
        for (int kt = 0; kt < 4; ++kt) {
            *(uint2*)(pbse + (kt * 2 + (quad >> 1)) * 256 + li * 16 + (quad & 1) * 8) =
                make_uint2(pkbf(pr[kt][0], pr[kt][1]), pkbf(pr[kt][2], pr[kt][3]));
        }
        s8v pf0 = *(const s8v*)(pbse + lane * 16);
        s8v pf1 = *(const s8v*)(pbse + 1024 + lane * 16);

#pragma unroll
        for (int f = 0; f < 4; ++f) {
            const unsigned short* vrow = Vc + (f * 16 + li) * 64;
            s8v v0 = *(const s8v*)(vrow + swz0);
            s8v v1 = *(const s8v*)(vrow + swz1);
            c_o[f] = __builtin_amdgcn_mfma_f32_16x16x32_bf16(v0, pf0, c_o[f], 0, 0, 0);
            c_o[f] = __builtin_amdgcn_mfma_f32_16x16x32_bf16(v1, pf1, c_o[f], 0, 0, 0);
        }

        __syncthreads();
    }

    lsum += __shfl_xor(lsum, 16);
    lsum += __shfl_xor(lsum, 32);

    if (nc == 1) {
        const float inv = 1.0f / lsum;
        float* orow = out + (base + qrow) * HS + quad * 4;
#pragma unroll
        for (int f = 0; f < 4; ++f) {
            f4v res = c_o[f];
            res[0] *= inv; res[1] *= inv; res[2] *= inv; res[3] *= inv;
            *(f4v*)(orow + f * 16) = res;
        }
    } else {
        const int local = (qt < 16) ? (qt - 8) * 2 + c
                        : (qt < 24) ? 16 + (qt - 16) * 3 + c
                                    : 40 + (qt - 24) * 4 + c;
        const int pidx = b * 72 + local;
        float* pc = pbuf + (size_t)pidx * 4096 + (w * 16 + li) * 64;
#pragma unroll
        for (int f = 0; f < 4; ++f)
            *(f4v*)(pc + f * 16 + quad * 4) = c_o[f];
        if (quad == 0)
            lsbuf[(size_t)pidx * 64 + w * 16 + li] = lsum;
    }
}

// ---------------- Partial combine + normalize (qt >= 8) ----------------
__global__ __launch_bounds__(256) void attn_reduce(
    const float* __restrict__ pbuf, const float* __restrict__ lsbuf,
    float* __restrict__ out)
{
    const int g = blockIdx.x;            // 384 = 16 batches * 24 q-tiles
    const int b = g / 24;
    const int r = g - b * 24;
    int qt, lbase, nc;
    if (r < 8)       { qt = 8 + r;        lbase = 2 * r;            nc = 2; }
    else if (r < 16) { qt = 16 + (r - 8); lbase = 16 + 3 * (r - 8); nc = 3; }
    else             { qt = 24 + (r - 16); lbase = 40 + 4 * (r - 16); nc = 4; }
    const int pidx0 = b * 72 + lbase;

    const int tid = threadIdx.x;
    const int row = tid >> 2;
    const int seg = tid & 3;

    float4 acc[4];
#pragma unroll
    for (int j = 0; j < 4; ++j) acc[j] = make_float4(0.f, 0.f, 0.f, 0.f);
    float ls = 0.f;

    for (int cc = 0; cc < nc; ++cc) {
        const float* pc = pbuf + (size_t)(pidx0 + cc) * 4096 + row * 64 + seg * 16;
#pragma unroll
        for (int j = 0; j < 4; ++j) {
            float4 v = *(const float4*)(pc + j * 4);
            acc[j].x += v.x; acc[j].y += v.y; acc[j].z += v.z; acc[j].w += v.w;
        }
        ls += lsbuf[(size_t)(pidx0 + cc) * 64 + row];
    }
    const float inv = 1.0f / ls;
    float* orow = out + ((size_t)b * TSEQ + (qt << 6) + row) * HS + seg * 16;
#pragma unroll
    for (int j = 0; j < 4; ++j) {
        *(float4*)(orow + j * 4) = make_float4(acc[j].x * inv, acc[j].y * inv,
                                               acc[j].z * inv, acc[j].w * inv);
    }
}

extern "C" void kernel_launch(void* const* d_in, const int* in_sizes, int n_in,
                              void* d_out, int out_size, void* d_ws, size_t ws_size,
                              hipStream_t stream) {
    const float* x  = (const float*)d_in[0];
    const float* Wk = (const float*)d_in[1];
    const float* bk = (const float*)d_in[2];
    const float* Wq = (const float*)d_in[3];
    const float* bq = (const float*)d_in[4];
    const float* Wv = (const float*)d_in[5];
    const float* bv = (const float*)d_in[6];
    float* outp = (float*)d_out;

    const size_t elems = (size_t)16 * TSEQ * HS;  // 2M per tensor
    unsigned short* qbuf = (unsigned short*)d_ws;
    unsigned short* kbuf = qbuf + elems;
    unsigned short* vbuf = kbuf + elems;          // transposed [b][dim][t]
    unsigned short* wtb  = vbuf + elems;          // tiled [12][4][64] granules
    float* pbuf  = (float*)(wtb + 32768);         // [1152][64][64] fp32 partials
    float* lsbuf = pbuf + (size_t)1152 * 4096;    // [1152][64] lsums

    wconv<<<12, 256, 0, stream>>>(Wq, Wk, Wv, wtb);
    qkv<<<2048, 64, 0, stream>>>(x, wtb, bq, bk, bv, qbuf, kbuf, vbuf);
    attn_main<<<1280, 256, 0, stream>>>(qbuf, kbuf, vbuf, outp, pbuf, lsbuf);
    attn_reduce<<<384, 256, 0, stream>>>(pbuf, lsbuf, outp);
}